// Round 2
// baseline (935.299 us; speedup 1.0000x reference)
//
#include <hip/hip_runtime.h>
#include <hip/hip_bf16.h>

#define B_ 32
#define S_ 512
#define W_ 20
#define T_ 16
#define E_ 300
#define H_ 128
#define M_ (B_*S_)   // 16384

// workspace offsets (floats)
#define OFF_GX        0ul          // [M,768]   12582912 f  (dead after GRU -> reused by SRPART)
#define OFF_X         12582912ul   // [M,300]   4915200 f   (dead after gx GEMM -> reused by CTX)
#define OFF_SENT      17498112ul   // [M,256]   4194304 f
#define OFF_LASTF     21692416ul   // [32,128]
#define OFF_LASTB     21696512ul   // [32,128]
#define OFF_DOCVEC    21700608ul   // [32,256]
#define OFF_TOPICMAT  21708800ul   // [32,16,256]
#define OFF_DOCPART   21839872ul   // [32,512]
#define OFF_TOPICPART 21856256ul   // [32,16,512]
#define OFF_SEG       22118400ul   // [M] int
#define OFF_WTIH      22134784ul   // [300,768]
#define OFF_BIASIH    22365184ul   // [768]
#define OFF_W1T       22365952ul   // [512,128]
#define OFF_H         22431488ul   // [M,128]
#define OFF_SRPART    0ul          // overlay GX: [M,512]
#define OFF_CTX       OFF_X        // overlay X:  [M,256]

// ---------------- prep: transposes + bias concat ----------------
__global__ void prep_kernel(const float* __restrict__ Wih_f, const float* __restrict__ Wih_b,
                            const float* __restrict__ bih_f, const float* __restrict__ bih_b,
                            const float* __restrict__ W1,
                            float* __restrict__ Wt_ih, float* __restrict__ bias_ih,
                            float* __restrict__ W1t) {
  int idx = blockIdx.x * 256 + threadIdx.x;
  if (idx < E_ * 768) {
    int k = idx / 768, g = idx % 768;
    Wt_ih[idx] = (g < 384) ? Wih_f[g * E_ + k] : Wih_b[(g - 384) * E_ + k];
  }
  if (idx < 768) bias_ih[idx] = (idx < 384) ? bih_f[idx] : bih_b[idx - 384];
  if (idx < 512 * 128) { int k = idx / 128, j = idx % 128; W1t[idx] = W1[j * 512 + k]; }
}

// ---------------- embedding mean ----------------
__global__ void embed_mean_kernel(const int* __restrict__ wid, const float* __restrict__ emb,
                                  float* __restrict__ x) {
  int m = blockIdx.x;               // 16384 sentences
  const int* ids = wid + (size_t)m * W_;
  int e = threadIdx.x;              // 128 threads
  float s0 = 0.f, s1 = 0.f, s2 = 0.f;
  for (int w = 0; w < W_; w++) {
    const float* row = emb + (size_t)ids[w] * E_;
    s0 += row[e];
    s1 += row[e + 128];
    if (e < E_ - 256) s2 += row[e + 256];
  }
  const float inv = 1.0f / (float)W_;
  float* xr = x + (size_t)m * E_;
  xr[e] = s0 * inv; xr[e + 128] = s1 * inv; if (e < E_ - 256) xr[e + 256] = s2 * inv;
}

// ---------------- generic tiled f32 GEMM: C = A[M,K] @ B[K,N] (+bias)(+C)(relu) ----------------
template<bool BIAS, bool ACCUM, bool RELU>
__global__ __launch_bounds__(256) void gemm64(
    const float* __restrict__ A, int lda,
    const float* __restrict__ B, int ldb,
    float* __restrict__ C, int ldc,
    const float* __restrict__ bias,
    int M, int N, int K) {
  __shared__ float As[16][68];
  __shared__ float Bs[16][68];
  const int tid = threadIdx.x;
  const int n0 = blockIdx.x * 64, m0 = blockIdx.y * 64;
  const int tx = tid & 15, ty = tid >> 4;
  const int am = tid >> 2, ak = (tid & 3) << 2;
  const int bk = tid >> 4, bn = (tid & 15) << 2;
  float acc[4][4] = {};
  for (int k0 = 0; k0 < K; k0 += 16) {
    float4 av = make_float4(0.f, 0.f, 0.f, 0.f);
    int arow = m0 + am;
    if (arow < M) {
      if (k0 + ak + 3 < K) {
        av = *(const float4*)(A + (size_t)arow * lda + k0 + ak);
      } else {
        float tmp[4] = {0.f, 0.f, 0.f, 0.f};
        #pragma unroll
        for (int i2 = 0; i2 < 4; i2++) { int k = k0 + ak + i2; if (k < K) tmp[i2] = A[(size_t)arow * lda + k]; }
        av = make_float4(tmp[0], tmp[1], tmp[2], tmp[3]);
      }
    }
    As[ak + 0][am] = av.x; As[ak + 1][am] = av.y; As[ak + 2][am] = av.z; As[ak + 3][am] = av.w;
    float4 bv = make_float4(0.f, 0.f, 0.f, 0.f);
    {
      int k = k0 + bk;
      if (k < K) bv = *(const float4*)(B + (size_t)k * ldb + n0 + bn);
    }
    *(float4*)&Bs[bk][bn] = bv;
    __syncthreads();
    #pragma unroll
    for (int kk = 0; kk < 16; kk++) {
      float4 a = *(const float4*)&As[kk][ty << 2];
      float4 b = *(const float4*)&Bs[kk][tx << 2];
      acc[0][0] = fmaf(a.x, b.x, acc[0][0]); acc[0][1] = fmaf(a.x, b.y, acc[0][1]);
      acc[0][2] = fmaf(a.x, b.z, acc[0][2]); acc[0][3] = fmaf(a.x, b.w, acc[0][3]);
      acc[1][0] = fmaf(a.y, b.x, acc[1][0]); acc[1][1] = fmaf(a.y, b.y, acc[1][1]);
      acc[1][2] = fmaf(a.y, b.z, acc[1][2]); acc[1][3] = fmaf(a.y, b.w, acc[1][3]);
      acc[2][0] = fmaf(a.z, b.x, acc[2][0]); acc[2][1] = fmaf(a.z, b.y, acc[2][1]);
      acc[2][2] = fmaf(a.z, b.z, acc[2][2]); acc[2][3] = fmaf(a.z, b.w, acc[2][3]);
      acc[3][0] = fmaf(a.w, b.x, acc[3][0]); acc[3][1] = fmaf(a.w, b.y, acc[3][1]);
      acc[3][2] = fmaf(a.w, b.z, acc[3][2]); acc[3][3] = fmaf(a.w, b.w, acc[3][3]);
    }
    __syncthreads();
  }
  float4 bias4 = make_float4(0.f, 0.f, 0.f, 0.f);
  if (BIAS) bias4 = *(const float4*)(bias + n0 + (tx << 2));
  #pragma unroll
  for (int i = 0; i < 4; i++) {
    int row = m0 + (ty << 2) + i;
    if (row >= M) break;
    float* cp = C + (size_t)row * ldc + n0 + (tx << 2);
    float4 v = make_float4(acc[i][0], acc[i][1], acc[i][2], acc[i][3]);
    if (BIAS) { v.x += bias4.x; v.y += bias4.y; v.z += bias4.z; v.w += bias4.w; }
    if (ACCUM) { float4 o = *(const float4*)cp; v.x += o.x; v.y += o.y; v.z += o.z; v.w += o.w; }
    if (RELU) { v.x = fmaxf(v.x, 0.f); v.y = fmaxf(v.y, 0.f); v.z = fmaxf(v.z, 0.f); v.w = fmaxf(v.w, 0.f); }
    *(float4*)cp = v;
  }
}

// ---------------- GRU recurrence v2: readlane broadcast, 64 blocks x 256 threads ----------------
// Thread t: j = t&127 (gate row), q = half of h-range. Waves 0,1 are "owners"
// (j=t, q matches own j-range -> h kept in register, no LDS read). Waves 2,3
// compute the complementary half-dots and pass partials through LDS.
__global__ __launch_bounds__(256, 1) void gru_kernel(
    const float* __restrict__ gxbuf,   // [M,768] : row b*512+s, cols [dir*384 + g]
    const float* __restrict__ Whh_f, const float* __restrict__ Whh_b,
    const float* __restrict__ bhh_f, const float* __restrict__ bhh_b,
    float* __restrict__ sent_rep,      // [B,S,256]
    float* __restrict__ last_f, float* __restrict__ last_b) {
  const int bid = blockIdx.x;          // 64 = dir*32 + b
  const int dir = bid >> 5, b = bid & 31;
  const int t = threadIdx.x;           // 0..255
  const int j = t & 127;               // gate row 0..127
  const int lane = t & 63;
  const int q = ((t >> 6) ^ (t >> 7)) & 1;  // h-half index for this thread
  const int k0 = q << 6;
  const bool owner = (t < 128);
  const float* Whh = dir ? Whh_b : Whh_f;
  const float* bhh = dir ? bhh_b : bhh_f;

  // per-thread Whh slices: rows {j, 128+j, 256+j}, cols [k0, k0+64)
  float wr[64], wz[64], wn[64];
  #pragma unroll
  for (int kk = 0; kk < 64; kk += 4) {
    float4 a = *(const float4*)(Whh + (size_t)j * 128 + k0 + kk);
    wr[kk] = a.x; wr[kk + 1] = a.y; wr[kk + 2] = a.z; wr[kk + 3] = a.w;
    float4 c = *(const float4*)(Whh + (size_t)(128 + j) * 128 + k0 + kk);
    wz[kk] = c.x; wz[kk + 1] = c.y; wz[kk + 2] = c.z; wz[kk + 3] = c.w;
    float4 d = *(const float4*)(Whh + (size_t)(256 + j) * 128 + k0 + kk);
    wn[kk] = d.x; wn[kk + 1] = d.y; wn[kk + 2] = d.z; wn[kk + 3] = d.w;
  }
  float bhr = 0.f, bhz = 0.f, bhn = 0.f;
  if (owner) { bhr = bhh[j]; bhz = bhh[128 + j]; bhn = bhh[256 + j]; }

  __shared__ float hbuf[128];
  __shared__ float rp[128], zp[128], np_[128];
  if (t < 128) hbuf[t] = 0.f;
  __syncthreads();

  float hown = 0.f;                    // owners: h[j] carried in register
  const float* gx0 = gxbuf + (size_t)b * 512 * 768 + dir * 384 + j;
  int ts = dir ? 511 : 0;
  const int stp = dir ? -1 : 1;
  float* srow = sent_rep + (size_t)b * 512 * 256 + dir * 128;

  float gr_c = 0.f, gz_c = 0.f, gn_c = 0.f, gr_1 = 0.f, gz_1 = 0.f, gn_1 = 0.f;
  if (owner) {
    const float* p0 = gx0 + (size_t)ts * 768;
    gr_c = p0[0]; gz_c = p0[128]; gn_c = p0[256];
    const float* p1 = gx0 + (size_t)(ts + stp) * 768;
    gr_1 = p1[0]; gz_1 = p1[128]; gn_1 = p1[256];
  }

  for (int s = 0; s < 512; s++) {
    float gr_2 = 0.f, gz_2 = 0.f, gn_2 = 0.f;
    if (owner && s + 2 < 512) {
      const float* p2 = gx0 + (size_t)(ts + 2 * stp) * 768;
      gr_2 = p2[0]; gz_2 = p2[128]; gn_2 = p2[256];
    }
    // h-half for this wave: owners carry it in-register, non-owners read LDS
    float hreg = owner ? hown : hbuf[k0 + lane];
    float ar = 0.f, az = 0.f, an = 0.f;
    #pragma unroll
    for (int kk = 0; kk < 64; kk++) {
      float hv = __int_as_float(__builtin_amdgcn_readlane(__float_as_int(hreg), kk));
      ar = fmaf(wr[kk], hv, ar);
      az = fmaf(wz[kk], hv, az);
      an = fmaf(wn[kk], hv, an);
    }
    if (!owner) { rp[j] = ar; zp[j] = az; np_[j] = an; }
    __syncthreads();  // A: partials visible; prior-step hbuf reads drained
    if (owner) {
      ar += rp[j]; az += zp[j]; an += np_[j];
      float r = 1.f / (1.f + expf(-(gr_c + ar + bhr)));
      float z = 1.f / (1.f + expf(-(gz_c + az + bhz)));
      float n = tanhf(gn_c + r * (an + bhn));
      float hnew = (1.f - z) * n + z * hown;
      hown = hnew;
      hbuf[j] = hnew;
      srow[(size_t)ts * 256 + j] = hnew;
    }
    __syncthreads();  // B: new hbuf visible to non-owners
    ts += stp;
    gr_c = gr_1; gz_c = gz_1; gn_c = gn_1;
    gr_1 = gr_2; gz_1 = gz_2; gn_1 = gn_2;
  }
  if (owner) (dir ? last_b : last_f)[b * 128 + j] = hown;
}

// ---------------- doc_vec with torch .view batch-scramble ----------------
__global__ void docvec_kernel(const float* __restrict__ last_f, const float* __restrict__ last_b,
                              float* __restrict__ doc_vec) {
  int idx = blockIdx.x * 256 + threadIdx.x;  // 8192
  int i = idx >> 8, c = idx & 255;
  const float* src = (i < 16) ? last_f : last_b;
  int ii = (i < 16) ? i : i - 16;
  int bb = 2 * ii + (c >> 7);
  doc_vec[idx] = src[bb * 128 + (c & 127)];
}

// ---------------- topic_mat boundary diffs ----------------
__global__ void topicmat_kernel(const float* __restrict__ sent_rep, const int* __restrict__ tse,
                                float* __restrict__ topic_mat) {
  int bt = blockIdx.x;  // 512 = b*16+t
  int b = bt >> 4, t = bt & 15;
  int st = tse[(b * 16 + t) * 2 + 0];   // 1-based
  int en = tse[(b * 16 + t) * 2 + 1];
  int jj = threadIdx.x;                 // 0..255
  const float* sr = sent_rep + (size_t)b * 512 * 256;
  float val;
  if (jj < 128) {
    float a = sr[(size_t)(en - 1) * 256 + jj];
    float c = (st - 2 >= 0) ? sr[(size_t)(st - 2) * 256 + jj] : 0.f;
    val = a - c;
  } else {
    float a = sr[(size_t)(st - 1) * 256 + jj];
    float c = (en <= 511) ? sr[(size_t)en * 256 + jj] : 0.f;
    val = a - c;
  }
  topic_mat[(size_t)bt * 256 + jj] = val;
}

// ---------------- seg (searchsorted right - 1) ----------------
__global__ void seg_kernel(const int* __restrict__ tse, int* __restrict__ seg) {
  int idx = blockIdx.x * 256 + threadIdx.x;  // 16384
  int b = idx >> 9, s = idx & 511;
  int pos = s + 1, cnt = 0;
  for (int t = 0; t < T_; t++) cnt += (tse[(b * T_ + t) * 2] <= pos);
  int sg = cnt - 1; sg = sg < 0 ? 0 : (sg > T_ - 1 ? T_ - 1 : sg);
  seg[idx] = sg;
}

// ---------------- scores + ratios + context (wave per row) ----------------
__global__ void scores_ctx_kernel(const float* __restrict__ sr_part,     // [M,512]
                                  const float* __restrict__ doc_part,    // [32,512]
                                  const float* __restrict__ topic_part,  // [32,16,512]
                                  const float* __restrict__ v_att,       // [512]
                                  const float* __restrict__ doc_vec,     // [32,256]
                                  const float* __restrict__ topic_mat,   // [32,16,256]
                                  const int* __restrict__ seg,           // [M]
                                  float* __restrict__ context) {         // [M,256]
  int wid = threadIdx.x >> 6, lane = threadIdx.x & 63;
  int row = blockIdx.x * 4 + wid;
  int b = row >> 9;
  int sg = seg[row];
  const float* srp = sr_part + (size_t)row * 512;
  const float* dp = doc_part + (size_t)b * 512;
  const float* tp = topic_part + (size_t)(b * 16 + sg) * 512;
  float accd = 0.f, acct = 0.f;
  #pragma unroll
  for (int i = 0; i < 8; i++) {
    int n = lane + i * 64;
    float sp = srp[n], va = v_att[n];
    accd += tanhf(dp[n] + sp) * va;
    acct += tanhf(tp[n] + sp) * va;
  }
  #pragma unroll
  for (int off = 32; off; off >>= 1) { accd += __shfl_xor(accd, off); acct += __shfl_xor(acct, off); }
  float ssum = accd + acct;
  float rd = accd / ssum, rt = acct / ssum;
  const float* dv = doc_vec + (size_t)b * 256;
  const float* tm = topic_mat + (size_t)(b * 16 + sg) * 256;
  float* ctx = context + (size_t)row * 256;
  #pragma unroll
  for (int i = 0; i < 4; i++) {
    int jj = lane + i * 64;
    ctx[jj] = rd * dv[jj] + rt * tm[jj];
  }
}

// ---------------- logits: out = h . W2 + b2 (wave per row) ----------------
__global__ void logits_kernel(const float* __restrict__ h, const float* __restrict__ W2,
                              const float* __restrict__ b2, float* __restrict__ out, int M) {
  int wid = threadIdx.x >> 6, lane = threadIdx.x & 63;
  int row = blockIdx.x * 4 + wid;
  if (row >= M) return;
  const float* hp = h + (size_t)row * 128;
  float s = hp[lane] * W2[lane] + hp[lane + 64] * W2[lane + 64];
  #pragma unroll
  for (int off = 32; off; off >>= 1) s += __shfl_xor(s, off);
  if (lane == 0) out[row] = s + b2[0];
}

extern "C" void kernel_launch(void* const* d_in, const int* in_sizes, int n_in,
                              void* d_out, int out_size, void* d_ws, size_t ws_size,
                              hipStream_t stream) {
  const int*   word_ids = (const int*)d_in[0];
  const int*   tse      = (const int*)d_in[1];
  const float* emb      = (const float*)d_in[2];
  const float* Wih_f    = (const float*)d_in[3];
  const float* Whh_f    = (const float*)d_in[4];
  const float* bih_f    = (const float*)d_in[5];
  const float* bhh_f    = (const float*)d_in[6];
  const float* Wih_b    = (const float*)d_in[7];
  const float* Whh_b    = (const float*)d_in[8];
  const float* bih_b    = (const float*)d_in[9];
  const float* bhh_b    = (const float*)d_in[10];
  const float* W_att    = (const float*)d_in[11];
  const float* v_att    = (const float*)d_in[12];
  const float* W1       = (const float*)d_in[13];
  const float* b1       = (const float*)d_in[14];
  const float* W2       = (const float*)d_in[15];
  const float* b2       = (const float*)d_in[16];
  float* ws  = (float*)d_ws;
  float* out = (float*)d_out;

  prep_kernel<<<900, 256, 0, stream>>>(Wih_f, Wih_b, bih_f, bih_b, W1,
                                       ws + OFF_WTIH, ws + OFF_BIASIH, ws + OFF_W1T);
  embed_mean_kernel<<<M_, 128, 0, stream>>>(word_ids, emb, ws + OFF_X);
  // gx = x @ [Wih_f|Wih_b]^T + bias  -> [M,768]
  gemm64<true, false, false><<<dim3(12, 256), 256, 0, stream>>>(
      ws + OFF_X, E_, ws + OFF_WTIH, 768, ws + OFF_GX, 768, ws + OFF_BIASIH, M_, 768, E_);
  gru_kernel<<<64, 256, 0, stream>>>(ws + OFF_GX, Whh_f, Whh_b, bhh_f, bhh_b,
                                     ws + OFF_SENT, ws + OFF_LASTF, ws + OFF_LASTB);
  docvec_kernel<<<32, 256, 0, stream>>>(ws + OFF_LASTF, ws + OFF_LASTB, ws + OFF_DOCVEC);
  topicmat_kernel<<<512, 256, 0, stream>>>(ws + OFF_SENT, tse, ws + OFF_TOPICMAT);
  seg_kernel<<<64, 256, 0, stream>>>(tse, (int*)(ws + OFF_SEG));
  // doc_part = doc_vec @ W_att[0:256,:]
  gemm64<false, false, false><<<dim3(8, 1), 256, 0, stream>>>(
      ws + OFF_DOCVEC, 256, W_att, 512, ws + OFF_DOCPART, 512, nullptr, 32, 512, 256);
  // topic_part = topic_mat @ W_att[0:256,:]
  gemm64<false, false, false><<<dim3(8, 8), 256, 0, stream>>>(
      ws + OFF_TOPICMAT, 256, W_att, 512, ws + OFF_TOPICPART, 512, nullptr, 512, 512, 256);
  // sr_part = sent_rep @ W_att[256:512,:]
  gemm64<false, false, false><<<dim3(8, 256), 256, 0, stream>>>(
      ws + OFF_SENT, 256, W_att + 256 * 512, 512, ws + OFF_SRPART, 512, nullptr, M_, 512, 256);
  scores_ctx_kernel<<<M_ / 4, 256, 0, stream>>>(
      ws + OFF_SRPART, ws + OFF_DOCPART, ws + OFF_TOPICPART, v_att,
      ws + OFF_DOCVEC, ws + OFF_TOPICMAT, (const int*)(ws + OFF_SEG), ws + OFF_CTX);
  // h = relu(sent_rep @ W1t[0:256] + b1 + context @ W1t[256:512])
  gemm64<true, false, false><<<dim3(2, 256), 256, 0, stream>>>(
      ws + OFF_SENT, 256, ws + OFF_W1T, 128, ws + OFF_H, 128, b1, M_, 128, 256);
  gemm64<false, true, true><<<dim3(2, 256), 256, 0, stream>>>(
      ws + OFF_CTX, 256, ws + OFF_W1T + 256 * 128, 128, ws + OFF_H, 128, nullptr, M_, 128, 256);
  logits_kernel<<<M_ / 4, 256, 0, stream>>>(ws + OFF_H, W2, b2, out, M_);
}

// Round 3
// 873.258 us; speedup vs baseline: 1.0710x; 1.0710x over previous
//
#include <hip/hip_runtime.h>
#include <hip/hip_bf16.h>

#define B_ 32
#define S_ 512
#define W_ 20
#define T_ 16
#define E_ 300
#define H_ 128
#define M_ (B_*S_)   // 16384

// workspace offsets (floats)
#define OFF_GX        0ul          // [M,768]   12582912 f  (dead after GRU -> reused by SRPART)
#define OFF_X         12582912ul   // [M,300]   4915200 f   (dead after gx GEMM -> reused by CTX)
#define OFF_SENT      17498112ul   // [M,256]   4194304 f
#define OFF_LASTF     21692416ul   // [32,128]
#define OFF_LASTB     21696512ul   // [32,128]
#define OFF_DOCVEC    21700608ul   // [32,256]
#define OFF_TOPICMAT  21708800ul   // [32,16,256]
#define OFF_DOCPART   21839872ul   // [32,512]
#define OFF_TOPICPART 21856256ul   // [32,16,512]
#define OFF_SEG       22118400ul   // [M] int
#define OFF_WTIH      22134784ul   // [300,768]
#define OFF_BIASIH    22365184ul   // [768]
#define OFF_W1T       22365952ul   // [512,128]
#define OFF_H         22431488ul   // [M,128]
#define OFF_SRPART    0ul          // overlay GX: [M,512]
#define OFF_CTX       OFF_X        // overlay X:  [M,256]

// ---------------- prep: transposes + bias concat ----------------
__global__ void prep_kernel(const float* __restrict__ Wih_f, const float* __restrict__ Wih_b,
                            const float* __restrict__ bih_f, const float* __restrict__ bih_b,
                            const float* __restrict__ W1,
                            float* __restrict__ Wt_ih, float* __restrict__ bias_ih,
                            float* __restrict__ W1t) {
  int idx = blockIdx.x * 256 + threadIdx.x;
  if (idx < E_ * 768) {
    int k = idx / 768, g = idx % 768;
    Wt_ih[idx] = (g < 384) ? Wih_f[g * E_ + k] : Wih_b[(g - 384) * E_ + k];
  }
  if (idx < 768) bias_ih[idx] = (idx < 384) ? bih_f[idx] : bih_b[idx - 384];
  if (idx < 512 * 128) { int k = idx / 128, j = idx % 128; W1t[idx] = W1[j * 512 + k]; }
}

// ---------------- embedding mean ----------------
__global__ void embed_mean_kernel(const int* __restrict__ wid, const float* __restrict__ emb,
                                  float* __restrict__ x) {
  int m = blockIdx.x;               // 16384 sentences
  const int* ids = wid + (size_t)m * W_;
  int e = threadIdx.x;              // 128 threads
  float s0 = 0.f, s1 = 0.f, s2 = 0.f;
  for (int w = 0; w < W_; w++) {
    const float* row = emb + (size_t)ids[w] * E_;
    s0 += row[e];
    s1 += row[e + 128];
    if (e < E_ - 256) s2 += row[e + 256];
  }
  const float inv = 1.0f / (float)W_;
  float* xr = x + (size_t)m * E_;
  xr[e] = s0 * inv; xr[e + 128] = s1 * inv; if (e < E_ - 256) xr[e + 256] = s2 * inv;
}

// ---------------- generic tiled f32 GEMM: C = A[M,K] @ B[K,N] (+bias)(+C)(relu) ----------------
template<bool BIAS, bool ACCUM, bool RELU>
__global__ __launch_bounds__(256) void gemm64(
    const float* __restrict__ A, int lda,
    const float* __restrict__ B, int ldb,
    float* __restrict__ C, int ldc,
    const float* __restrict__ bias,
    int M, int N, int K) {
  __shared__ float As[16][68];
  __shared__ float Bs[16][68];
  const int tid = threadIdx.x;
  const int n0 = blockIdx.x * 64, m0 = blockIdx.y * 64;
  const int tx = tid & 15, ty = tid >> 4;
  const int am = tid >> 2, ak = (tid & 3) << 2;
  const int bk = tid >> 4, bn = (tid & 15) << 2;
  float acc[4][4] = {};
  for (int k0 = 0; k0 < K; k0 += 16) {
    float4 av = make_float4(0.f, 0.f, 0.f, 0.f);
    int arow = m0 + am;
    if (arow < M) {
      if (k0 + ak + 3 < K) {
        av = *(const float4*)(A + (size_t)arow * lda + k0 + ak);
      } else {
        float tmp[4] = {0.f, 0.f, 0.f, 0.f};
        #pragma unroll
        for (int i2 = 0; i2 < 4; i2++) { int k = k0 + ak + i2; if (k < K) tmp[i2] = A[(size_t)arow * lda + k]; }
        av = make_float4(tmp[0], tmp[1], tmp[2], tmp[3]);
      }
    }
    As[ak + 0][am] = av.x; As[ak + 1][am] = av.y; As[ak + 2][am] = av.z; As[ak + 3][am] = av.w;
    float4 bv = make_float4(0.f, 0.f, 0.f, 0.f);
    {
      int k = k0 + bk;
      if (k < K) bv = *(const float4*)(B + (size_t)k * ldb + n0 + bn);
    }
    *(float4*)&Bs[bk][bn] = bv;
    __syncthreads();
    #pragma unroll
    for (int kk = 0; kk < 16; kk++) {
      float4 a = *(const float4*)&As[kk][ty << 2];
      float4 b = *(const float4*)&Bs[kk][tx << 2];
      acc[0][0] = fmaf(a.x, b.x, acc[0][0]); acc[0][1] = fmaf(a.x, b.y, acc[0][1]);
      acc[0][2] = fmaf(a.x, b.z, acc[0][2]); acc[0][3] = fmaf(a.x, b.w, acc[0][3]);
      acc[1][0] = fmaf(a.y, b.x, acc[1][0]); acc[1][1] = fmaf(a.y, b.y, acc[1][1]);
      acc[1][2] = fmaf(a.y, b.z, acc[1][2]); acc[1][3] = fmaf(a.y, b.w, acc[1][3]);
      acc[2][0] = fmaf(a.z, b.x, acc[2][0]); acc[2][1] = fmaf(a.z, b.y, acc[2][1]);
      acc[2][2] = fmaf(a.z, b.z, acc[2][2]); acc[2][3] = fmaf(a.z, b.w, acc[2][3]);
      acc[3][0] = fmaf(a.w, b.x, acc[3][0]); acc[3][1] = fmaf(a.w, b.y, acc[3][1]);
      acc[3][2] = fmaf(a.w, b.z, acc[3][2]); acc[3][3] = fmaf(a.w, b.w, acc[3][3]);
    }
    __syncthreads();
  }
  float4 bias4 = make_float4(0.f, 0.f, 0.f, 0.f);
  if (BIAS) bias4 = *(const float4*)(bias + n0 + (tx << 2));
  #pragma unroll
  for (int i = 0; i < 4; i++) {
    int row = m0 + (ty << 2) + i;
    if (row >= M) break;
    float* cp = C + (size_t)row * ldc + n0 + (tx << 2);
    float4 v = make_float4(acc[i][0], acc[i][1], acc[i][2], acc[i][3]);
    if (BIAS) { v.x += bias4.x; v.y += bias4.y; v.z += bias4.z; v.w += bias4.w; }
    if (ACCUM) { float4 o = *(const float4*)cp; v.x += o.x; v.y += o.y; v.z += o.z; v.w += o.w; }
    if (RELU) { v.x = fmaxf(v.x, 0.f); v.y = fmaxf(v.y, 0.f); v.z = fmaxf(v.z, 0.f); v.w = fmaxf(v.w, 0.f); }
    *(float4*)cp = v;
  }
}

// ---------------- GRU recurrence v3 ----------------
// 32 blocks (one per batch doc) x 512 threads = 2 chains (dir 0/1), 8 waves,
// 2 waves/SIMD for latency hiding. Per chain: 256 threads, thread (j, half)
// computes half-dots (64 MACs) for gates r/z/n of row j. Weights held in 48
// named-index float4 registers (192 VGPR). h broadcast via uniform-address
// float4 LDS reads. Helpers (half=1) prefetch gx and fold it into partials
// (n-gate gx passed separately: r must not multiply it).
__global__ __launch_bounds__(512, 2) void gru_kernel(
    const float* __restrict__ gxbuf,   // [M,768] : row b*512+s, cols [dir*384 + g]
    const float* __restrict__ Whh_f, const float* __restrict__ Whh_b,
    const float* __restrict__ bhh_f, const float* __restrict__ bhh_b,
    float* __restrict__ sent_rep,      // [B,S,256]
    float* __restrict__ last_f, float* __restrict__ last_b) {
  const int b = blockIdx.x;            // 32
  const int t = threadIdx.x;           // 0..511
  const int dir = t >> 8;
  const int c = t & 255;
  const int j = c & 127;
  const int half = c >> 7;             // 0 = owner, 1 = helper
  const int k0 = half << 6;
  const bool owner = (half == 0);
  const float* Whh = dir ? Whh_b : Whh_f;
  const float* bhh = dir ? bhh_b : bhh_f;

  float4 wr4[16], wz4[16], wn4[16];
  #pragma unroll
  for (int kk = 0; kk < 16; kk++) {
    wr4[kk] = *(const float4*)(Whh + (size_t)j * 128 + k0 + kk * 4);
    wz4[kk] = *(const float4*)(Whh + (size_t)(128 + j) * 128 + k0 + kk * 4);
    wn4[kk] = *(const float4*)(Whh + (size_t)(256 + j) * 128 + k0 + kk * 4);
  }
  float bhr = 0.f, bhz = 0.f, bhn = 0.f;
  if (owner) { bhr = bhh[j]; bhz = bhh[128 + j]; bhn = bhh[256 + j]; }

  __shared__ float hbuf[2][128];
  __shared__ float rp[2][128], zp[2][128], np_[2][128], gxn[2][128];
  if (c < 128) hbuf[dir][c] = 0.f;
  __syncthreads();

  float hown = 0.f;                    // owners: h[j] carried in register
  const float* gx0 = gxbuf + (size_t)b * 512 * 768 + dir * 384 + j;
  int ts = dir ? 511 : 0;
  const int stp = dir ? -1 : 1;
  float* srow = sent_rep + (size_t)b * 512 * 256 + dir * 128;

  float gr_c = 0.f, gz_c = 0.f, gn_c = 0.f, gr_1 = 0.f, gz_1 = 0.f, gn_1 = 0.f;
  if (!owner) {
    const float* p0 = gx0 + (size_t)ts * 768;
    gr_c = p0[0]; gz_c = p0[128]; gn_c = p0[256];
    const float* p1 = gx0 + (size_t)(ts + stp) * 768;
    gr_1 = p1[0]; gz_1 = p1[128]; gn_1 = p1[256];
  }

  for (int s = 0; s < 512; s++) {
    float gr_2 = 0.f, gz_2 = 0.f, gn_2 = 0.f;
    if (!owner && s + 2 < 512) {
      const float* p2 = gx0 + (size_t)(ts + 2 * stp) * 768;
      gr_2 = p2[0]; gz_2 = p2[128]; gn_2 = p2[256];
    }
    // half-dots over h[k0..k0+64) via uniform-address LDS broadcast reads
    const float4* h4 = (const float4*)&hbuf[dir][k0];
    float ar = 0.f, az = 0.f, an = 0.f;
    #pragma unroll
    for (int kk = 0; kk < 16; kk++) {
      float4 hv = h4[kk];
      ar = fmaf(wr4[kk].x, hv.x, ar); ar = fmaf(wr4[kk].y, hv.y, ar);
      ar = fmaf(wr4[kk].z, hv.z, ar); ar = fmaf(wr4[kk].w, hv.w, ar);
      az = fmaf(wz4[kk].x, hv.x, az); az = fmaf(wz4[kk].y, hv.y, az);
      az = fmaf(wz4[kk].z, hv.z, az); az = fmaf(wz4[kk].w, hv.w, az);
      an = fmaf(wn4[kk].x, hv.x, an); an = fmaf(wn4[kk].y, hv.y, an);
      an = fmaf(wn4[kk].z, hv.z, an); an = fmaf(wn4[kk].w, hv.w, an);
    }
    if (!owner) {
      rp[dir][j] = ar + gr_c;          // fold gx_r into partial
      zp[dir][j] = az + gz_c;          // fold gx_z
      np_[dir][j] = an;                // Whh_n part only
      gxn[dir][j] = gn_c;              // gx_n kept separate (outside r*(...))
    }
    __syncthreads();  // A: partials visible; this step's hbuf reads drained
    if (owner) {
      float rfull = rp[dir][j] + ar + bhr;
      float zfull = zp[dir][j] + az + bhz;
      float nfull = np_[dir][j] + an + bhn;
      float gn = gxn[dir][j];
      float r = 1.f / (1.f + expf(-rfull));
      float z = 1.f / (1.f + expf(-zfull));
      float n = tanhf(gn + r * nfull);
      float hnew = (1.f - z) * n + z * hown;
      hown = hnew;
      hbuf[dir][j] = hnew;
      srow[(size_t)ts * 256 + j] = hnew;
    }
    __syncthreads();  // B: new hbuf visible to all
    ts += stp;
    gr_c = gr_1; gz_c = gz_1; gn_c = gn_1;
    gr_1 = gr_2; gz_1 = gz_2; gn_1 = gn_2;
  }
  if (owner) (dir ? last_b : last_f)[b * 128 + j] = hown;
}

// ---------------- doc_vec with torch .view batch-scramble ----------------
__global__ void docvec_kernel(const float* __restrict__ last_f, const float* __restrict__ last_b,
                              float* __restrict__ doc_vec) {
  int idx = blockIdx.x * 256 + threadIdx.x;  // 8192
  int i = idx >> 8, c = idx & 255;
  const float* src = (i < 16) ? last_f : last_b;
  int ii = (i < 16) ? i : i - 16;
  int bb = 2 * ii + (c >> 7);
  doc_vec[idx] = src[bb * 128 + (c & 127)];
}

// ---------------- topic_mat boundary diffs ----------------
__global__ void topicmat_kernel(const float* __restrict__ sent_rep, const int* __restrict__ tse,
                                float* __restrict__ topic_mat) {
  int bt = blockIdx.x;  // 512 = b*16+t
  int b = bt >> 4, t = bt & 15;
  int st = tse[(b * 16 + t) * 2 + 0];   // 1-based
  int en = tse[(b * 16 + t) * 2 + 1];
  int jj = threadIdx.x;                 // 0..255
  const float* sr = sent_rep + (size_t)b * 512 * 256;
  float val;
  if (jj < 128) {
    float a = sr[(size_t)(en - 1) * 256 + jj];
    float c = (st - 2 >= 0) ? sr[(size_t)(st - 2) * 256 + jj] : 0.f;
    val = a - c;
  } else {
    float a = sr[(size_t)(st - 1) * 256 + jj];
    float c = (en <= 511) ? sr[(size_t)en * 256 + jj] : 0.f;
    val = a - c;
  }
  topic_mat[(size_t)bt * 256 + jj] = val;
}

// ---------------- seg (searchsorted right - 1) ----------------
__global__ void seg_kernel(const int* __restrict__ tse, int* __restrict__ seg) {
  int idx = blockIdx.x * 256 + threadIdx.x;  // 16384
  int b = idx >> 9, s = idx & 511;
  int pos = s + 1, cnt = 0;
  for (int t = 0; t < T_; t++) cnt += (tse[(b * T_ + t) * 2] <= pos);
  int sg = cnt - 1; sg = sg < 0 ? 0 : (sg > T_ - 1 ? T_ - 1 : sg);
  seg[idx] = sg;
}

// ---------------- scores + ratios + context (wave per row) ----------------
__global__ void scores_ctx_kernel(const float* __restrict__ sr_part,     // [M,512]
                                  const float* __restrict__ doc_part,    // [32,512]
                                  const float* __restrict__ topic_part,  // [32,16,512]
                                  const float* __restrict__ v_att,       // [512]
                                  const float* __restrict__ doc_vec,     // [32,256]
                                  const float* __restrict__ topic_mat,   // [32,16,256]
                                  const int* __restrict__ seg,           // [M]
                                  float* __restrict__ context) {         // [M,256]
  int wid = threadIdx.x >> 6, lane = threadIdx.x & 63;
  int row = blockIdx.x * 4 + wid;
  int b = row >> 9;
  int sg = seg[row];
  const float* srp = sr_part + (size_t)row * 512;
  const float* dp = doc_part + (size_t)b * 512;
  const float* tp = topic_part + (size_t)(b * 16 + sg) * 512;
  float accd = 0.f, acct = 0.f;
  #pragma unroll
  for (int i = 0; i < 8; i++) {
    int n = lane + i * 64;
    float sp = srp[n], va = v_att[n];
    accd += tanhf(dp[n] + sp) * va;
    acct += tanhf(tp[n] + sp) * va;
  }
  #pragma unroll
  for (int off = 32; off; off >>= 1) { accd += __shfl_xor(accd, off); acct += __shfl_xor(acct, off); }
  float ssum = accd + acct;
  float rd = accd / ssum, rt = acct / ssum;
  const float* dv = doc_vec + (size_t)b * 256;
  const float* tm = topic_mat + (size_t)(b * 16 + sg) * 256;
  float* ctx = context + (size_t)row * 256;
  #pragma unroll
  for (int i = 0; i < 4; i++) {
    int jj = lane + i * 64;
    ctx[jj] = rd * dv[jj] + rt * tm[jj];
  }
}

// ---------------- logits: out = h . W2 + b2 (wave per row) ----------------
__global__ void logits_kernel(const float* __restrict__ h, const float* __restrict__ W2,
                              const float* __restrict__ b2, float* __restrict__ out, int M) {
  int wid = threadIdx.x >> 6, lane = threadIdx.x & 63;
  int row = blockIdx.x * 4 + wid;
  if (row >= M) return;
  const float* hp = h + (size_t)row * 128;
  float s = hp[lane] * W2[lane] + hp[lane + 64] * W2[lane + 64];
  #pragma unroll
  for (int off = 32; off; off >>= 1) s += __shfl_xor(s, off);
  if (lane == 0) out[row] = s + b2[0];
}

extern "C" void kernel_launch(void* const* d_in, const int* in_sizes, int n_in,
                              void* d_out, int out_size, void* d_ws, size_t ws_size,
                              hipStream_t stream) {
  const int*   word_ids = (const int*)d_in[0];
  const int*   tse      = (const int*)d_in[1];
  const float* emb      = (const float*)d_in[2];
  const float* Wih_f    = (const float*)d_in[3];
  const float* Whh_f    = (const float*)d_in[4];
  const float* bih_f    = (const float*)d_in[5];
  const float* bhh_f    = (const float*)d_in[6];
  const float* Wih_b    = (const float*)d_in[7];
  const float* Whh_b    = (const float*)d_in[8];
  const float* bih_b    = (const float*)d_in[9];
  const float* bhh_b    = (const float*)d_in[10];
  const float* W_att    = (const float*)d_in[11];
  const float* v_att    = (const float*)d_in[12];
  const float* W1       = (const float*)d_in[13];
  const float* b1       = (const float*)d_in[14];
  const float* W2       = (const float*)d_in[15];
  const float* b2       = (const float*)d_in[16];
  float* ws  = (float*)d_ws;
  float* out = (float*)d_out;

  prep_kernel<<<900, 256, 0, stream>>>(Wih_f, Wih_b, bih_f, bih_b, W1,
                                       ws + OFF_WTIH, ws + OFF_BIASIH, ws + OFF_W1T);
  embed_mean_kernel<<<M_, 128, 0, stream>>>(word_ids, emb, ws + OFF_X);
  // gx = x @ [Wih_f|Wih_b]^T + bias  -> [M,768]
  gemm64<true, false, false><<<dim3(12, 256), 256, 0, stream>>>(
      ws + OFF_X, E_, ws + OFF_WTIH, 768, ws + OFF_GX, 768, ws + OFF_BIASIH, M_, 768, E_);
  gru_kernel<<<32, 512, 0, stream>>>(ws + OFF_GX, Whh_f, Whh_b, bhh_f, bhh_b,
                                     ws + OFF_SENT, ws + OFF_LASTF, ws + OFF_LASTB);
  docvec_kernel<<<32, 256, 0, stream>>>(ws + OFF_LASTF, ws + OFF_LASTB, ws + OFF_DOCVEC);
  topicmat_kernel<<<512, 256, 0, stream>>>(ws + OFF_SENT, tse, ws + OFF_TOPICMAT);
  seg_kernel<<<64, 256, 0, stream>>>(tse, (int*)(ws + OFF_SEG));
  // doc_part = doc_vec @ W_att[0:256,:]
  gemm64<false, false, false><<<dim3(8, 1), 256, 0, stream>>>(
      ws + OFF_DOCVEC, 256, W_att, 512, ws + OFF_DOCPART, 512, nullptr, 32, 512, 256);
  // topic_part = topic_mat @ W_att[0:256,:]
  gemm64<false, false, false><<<dim3(8, 8), 256, 0, stream>>>(
      ws + OFF_TOPICMAT, 256, W_att, 512, ws + OFF_TOPICPART, 512, nullptr, 512, 512, 256);
  // sr_part = sent_rep @ W_att[256:512,:]
  gemm64<false, false, false><<<dim3(8, 256), 256, 0, stream>>>(
      ws + OFF_SENT, 256, W_att + 256 * 512, 512, ws + OFF_SRPART, 512, nullptr, M_, 512, 256);
  scores_ctx_kernel<<<M_ / 4, 256, 0, stream>>>(
      ws + OFF_SRPART, ws + OFF_DOCPART, ws + OFF_TOPICPART, v_att,
      ws + OFF_DOCVEC, ws + OFF_TOPICMAT, (const int*)(ws + OFF_SEG), ws + OFF_CTX);
  // h = relu(sent_rep @ W1t[0:256] + b1 + context @ W1t[256:512])
  gemm64<true, false, false><<<dim3(2, 256), 256, 0, stream>>>(
      ws + OFF_SENT, 256, ws + OFF_W1T, 128, ws + OFF_H, 128, b1, M_, 128, 256);
  gemm64<false, true, true><<<dim3(2, 256), 256, 0, stream>>>(
      ws + OFF_CTX, 256, ws + OFF_W1T + 256 * 128, 128, ws + OFF_H, 128, nullptr, M_, 128, 256);
  logits_kernel<<<M_ / 4, 256, 0, stream>>>(ws + OFF_H, W2, b2, out, M_);
}

// Round 4
// 733.657 us; speedup vs baseline: 1.2748x; 1.1903x over previous
//
#include <hip/hip_runtime.h>
#include <hip/hip_bf16.h>

#define B_ 32
#define S_ 512
#define W_ 20
#define T_ 16
#define E_ 300
#define H_ 128
#define M_ (B_*S_)   // 16384

// workspace offsets (floats)
#define OFF_GX        0ul          // [M,768]   12582912 f  (dead after GRU -> reused by SRPART)
#define OFF_X         12582912ul   // [M,300]   4915200 f   (dead after gx GEMM -> reused by CTX)
#define OFF_SENT      17498112ul   // [M,256]   4194304 f
#define OFF_LASTF     21692416ul   // [32,128]
#define OFF_LASTB     21696512ul   // [32,128]
#define OFF_DOCVEC    21700608ul   // [32,256]
#define OFF_TOPICMAT  21708800ul   // [32,16,256]
#define OFF_DOCPART   21839872ul   // [32,512]
#define OFF_TOPICPART 21856256ul   // [32,16,512]
#define OFF_SEG       22118400ul   // [M] int
#define OFF_WTIH      22134784ul   // [300,768]
#define OFF_BIASIH    22365184ul   // [768]
#define OFF_W1T       22365952ul   // [512,128]
#define OFF_H         22431488ul   // [M,128]
#define OFF_SRPART    0ul          // overlay GX: [M,512]
#define OFF_CTX       OFF_X        // overlay X:  [M,256]

// ---------------- prep: transposes + bias concat ----------------
__global__ void prep_kernel(const float* __restrict__ Wih_f, const float* __restrict__ Wih_b,
                            const float* __restrict__ bih_f, const float* __restrict__ bih_b,
                            const float* __restrict__ W1,
                            float* __restrict__ Wt_ih, float* __restrict__ bias_ih,
                            float* __restrict__ W1t) {
  int idx = blockIdx.x * 256 + threadIdx.x;
  if (idx < E_ * 768) {
    int k = idx / 768, g = idx % 768;
    Wt_ih[idx] = (g < 384) ? Wih_f[g * E_ + k] : Wih_b[(g - 384) * E_ + k];
  }
  if (idx < 768) bias_ih[idx] = (idx < 384) ? bih_f[idx] : bih_b[idx - 384];
  if (idx < 512 * 128) { int k = idx / 128, j = idx % 128; W1t[idx] = W1[j * 512 + k]; }
}

// ---------------- embedding mean ----------------
__global__ void embed_mean_kernel(const int* __restrict__ wid, const float* __restrict__ emb,
                                  float* __restrict__ x) {
  int m = blockIdx.x;               // 16384 sentences
  const int* ids = wid + (size_t)m * W_;
  int e = threadIdx.x;              // 128 threads
  float s0 = 0.f, s1 = 0.f, s2 = 0.f;
  for (int w = 0; w < W_; w++) {
    const float* row = emb + (size_t)ids[w] * E_;
    s0 += row[e];
    s1 += row[e + 128];
    if (e < E_ - 256) s2 += row[e + 256];
  }
  const float inv = 1.0f / (float)W_;
  float* xr = x + (size_t)m * E_;
  xr[e] = s0 * inv; xr[e + 128] = s1 * inv; if (e < E_ - 256) xr[e + 256] = s2 * inv;
}

// ---------------- generic tiled f32 GEMM: C = A[M,K] @ B[K,N] (+bias)(+C)(relu) ----------------
template<bool BIAS, bool ACCUM, bool RELU>
__global__ __launch_bounds__(256) void gemm64(
    const float* __restrict__ A, int lda,
    const float* __restrict__ B, int ldb,
    float* __restrict__ C, int ldc,
    const float* __restrict__ bias,
    int M, int N, int K) {
  __shared__ float As[16][68];
  __shared__ float Bs[16][68];
  const int tid = threadIdx.x;
  const int n0 = blockIdx.x * 64, m0 = blockIdx.y * 64;
  const int tx = tid & 15, ty = tid >> 4;
  const int am = tid >> 2, ak = (tid & 3) << 2;
  const int bk = tid >> 4, bn = (tid & 15) << 2;
  float acc[4][4] = {};
  for (int k0 = 0; k0 < K; k0 += 16) {
    float4 av = make_float4(0.f, 0.f, 0.f, 0.f);
    int arow = m0 + am;
    if (arow < M) {
      if (k0 + ak + 3 < K) {
        av = *(const float4*)(A + (size_t)arow * lda + k0 + ak);
      } else {
        float tmp[4] = {0.f, 0.f, 0.f, 0.f};
        #pragma unroll
        for (int i2 = 0; i2 < 4; i2++) { int k = k0 + ak + i2; if (k < K) tmp[i2] = A[(size_t)arow * lda + k]; }
        av = make_float4(tmp[0], tmp[1], tmp[2], tmp[3]);
      }
    }
    As[ak + 0][am] = av.x; As[ak + 1][am] = av.y; As[ak + 2][am] = av.z; As[ak + 3][am] = av.w;
    float4 bv = make_float4(0.f, 0.f, 0.f, 0.f);
    {
      int k = k0 + bk;
      if (k < K) bv = *(const float4*)(B + (size_t)k * ldb + n0 + bn);
    }
    *(float4*)&Bs[bk][bn] = bv;
    __syncthreads();
    #pragma unroll
    for (int kk = 0; kk < 16; kk++) {
      float4 a = *(const float4*)&As[kk][ty << 2];
      float4 b = *(const float4*)&Bs[kk][tx << 2];
      acc[0][0] = fmaf(a.x, b.x, acc[0][0]); acc[0][1] = fmaf(a.x, b.y, acc[0][1]);
      acc[0][2] = fmaf(a.x, b.z, acc[0][2]); acc[0][3] = fmaf(a.x, b.w, acc[0][3]);
      acc[1][0] = fmaf(a.y, b.x, acc[1][0]); acc[1][1] = fmaf(a.y, b.y, acc[1][1]);
      acc[1][2] = fmaf(a.y, b.z, acc[1][2]); acc[1][3] = fmaf(a.y, b.w, acc[1][3]);
      acc[2][0] = fmaf(a.z, b.x, acc[2][0]); acc[2][1] = fmaf(a.z, b.y, acc[2][1]);
      acc[2][2] = fmaf(a.z, b.z, acc[2][2]); acc[2][3] = fmaf(a.z, b.w, acc[2][3]);
      acc[3][0] = fmaf(a.w, b.x, acc[3][0]); acc[3][1] = fmaf(a.w, b.y, acc[3][1]);
      acc[3][2] = fmaf(a.w, b.z, acc[3][2]); acc[3][3] = fmaf(a.w, b.w, acc[3][3]);
    }
    __syncthreads();
  }
  float4 bias4 = make_float4(0.f, 0.f, 0.f, 0.f);
  if (BIAS) bias4 = *(const float4*)(bias + n0 + (tx << 2));
  #pragma unroll
  for (int i = 0; i < 4; i++) {
    int row = m0 + (ty << 2) + i;
    if (row >= M) break;
    float* cp = C + (size_t)row * ldc + n0 + (tx << 2);
    float4 v = make_float4(acc[i][0], acc[i][1], acc[i][2], acc[i][3]);
    if (BIAS) { v.x += bias4.x; v.y += bias4.y; v.z += bias4.z; v.w += bias4.w; }
    if (ACCUM) { float4 o = *(const float4*)cp; v.x += o.x; v.y += o.y; v.z += o.z; v.w += o.w; }
    if (RELU) { v.x = fmaxf(v.x, 0.f); v.y = fmaxf(v.y, 0.f); v.z = fmaxf(v.z, 0.f); v.w = fmaxf(v.w, 0.f); }
    *(float4*)cp = v;
  }
}

// ---------------- GRU recurrence v4: in-wave quad reduce ----------------
// 64 blocks = (dir, doc), 512 threads. Wave holds 16 rows x 4 k-quarters:
// lane = (row&15) + 16*q, row j = wave*16 + (lane&15). Each thread holds 96
// weight floats (rows j,128+j,256+j, cols [32q,32q+32)) pinned in VGPRs via
// empty asm (defeats remat), with amdgpu_waves_per_eu(2,2) so the scheduler
// doesn't chase occupancy. Reduction via shfl_xor(16/32); all 4 lanes of a
// row compute hnew redundantly (h_prev carried in-register). Double-buffered
// h in LDS -> ONE barrier per step.
#define PIN4(v) asm volatile("" : "+v"((v).x), "+v"((v).y), "+v"((v).z), "+v"((v).w))
__global__ __launch_bounds__(512) __attribute__((amdgpu_waves_per_eu(2, 2)))
void gru_kernel(
    const float* __restrict__ gxbuf,   // [M,768] : row b*512+s, cols [dir*384 + gate*128 + j]
    const float* __restrict__ Whh_f, const float* __restrict__ Whh_b,
    const float* __restrict__ bhh_f, const float* __restrict__ bhh_b,
    float* __restrict__ sent_rep,      // [B,S,256]
    float* __restrict__ last_f, float* __restrict__ last_b) {
  const int bid = blockIdx.x;          // 64 = dir*32 + b
  const int dir = bid >> 5, b = bid & 31;
  const int t = threadIdx.x;           // 0..511
  const int wave = t >> 6;
  const int lane = t & 63;
  const int q = lane >> 4;             // k-quarter 0..3
  const int j = (wave << 4) + (lane & 15);  // gate row 0..127
  const int k0 = q << 5;
  const float* Whh = dir ? Whh_b : Whh_f;
  const float* bhh = dir ? bhh_b : bhh_f;

  // 96 weight floats per thread, asm-pinned so they cannot be rematerialized
  float4 wr4[8], wz4[8], wn4[8];
  #pragma unroll
  for (int i = 0; i < 8; i++) {
    wr4[i] = *(const float4*)(Whh + (size_t)j * 128 + k0 + i * 4);
    wz4[i] = *(const float4*)(Whh + (size_t)(128 + j) * 128 + k0 + i * 4);
    wn4[i] = *(const float4*)(Whh + (size_t)(256 + j) * 128 + k0 + i * 4);
  }
  #pragma unroll
  for (int i = 0; i < 8; i++) { PIN4(wr4[i]); PIN4(wz4[i]); PIN4(wn4[i]); }

  const float bhr = bhh[j], bhz = bhh[128 + j], bhn = bhh[256 + j];
  // gx gate handled by this lane: q1->r(0), q2->z(1), q3->n(2), q0->dup n
  const int gate = q ? (q - 1) : 2;
  const float mr = (q == 1) ? 1.f : 0.f;   // fold masks (pre-butterfly)
  const float mz = (q == 2) ? 1.f : 0.f;
  const float* gxp = gxbuf + (size_t)b * 512 * 768 + dir * 384 + gate * 128 + j;

  __shared__ float hbuf[2][128];
  if (t < 128) hbuf[0][t] = 0.f;
  __syncthreads();

  float hprev = 0.f;                   // h[j], replicated in all 4 lanes of the row
  int ts = dir ? 511 : 0;
  const int stp = dir ? -1 : 1;
  float* srow = sent_rep + (size_t)b * 512 * 256 + dir * 128;

  float gx_c = gxp[(size_t)ts * 768];
  float gx_1 = gxp[(size_t)(ts + stp) * 768];

  #pragma unroll 1
  for (int s = 0; s < 512; s++) {
    float gx_2 = 0.f;
    if (s + 2 < 512) gx_2 = gxp[(size_t)(ts + 2 * stp) * 768];
    // quarter-dots over h[k0..k0+32)
    const float4* h4 = (const float4*)(&hbuf[s & 1][k0]);
    float pr = 0.f, pz = 0.f, pn = 0.f;
    #pragma unroll
    for (int i = 0; i < 8; i++) {
      float4 hv = h4[i];
      pr = fmaf(wr4[i].x, hv.x, pr); pr = fmaf(wr4[i].y, hv.y, pr);
      pr = fmaf(wr4[i].z, hv.z, pr); pr = fmaf(wr4[i].w, hv.w, pr);
      pz = fmaf(wz4[i].x, hv.x, pz); pz = fmaf(wz4[i].y, hv.y, pz);
      pz = fmaf(wz4[i].z, hv.z, pz); pz = fmaf(wz4[i].w, hv.w, pz);
      pn = fmaf(wn4[i].x, hv.x, pn); pn = fmaf(wn4[i].y, hv.y, pn);
      pn = fmaf(wn4[i].z, hv.z, pn); pn = fmaf(wn4[i].w, hv.w, pn);
    }
    // fold gx_r / gx_z into the owning lane's partial
    pr = fmaf(mr, gx_c, pr);
    pz = fmaf(mz, gx_c, pz);
    // in-wave reduction across the 4 quarters
    pr += __shfl_xor(pr, 16); pr += __shfl_xor(pr, 32);
    pz += __shfl_xor(pz, 16); pz += __shfl_xor(pz, 32);
    pn += __shfl_xor(pn, 16); pn += __shfl_xor(pn, 32);
    float gn = __shfl(gx_c, (lane & 15) + 48);   // gx_n from the q=3 lane
    // all 4 lanes of the row compute hnew identically
    float r = 1.f / (1.f + expf(-(pr + bhr)));
    float z = 1.f / (1.f + expf(-(pz + bhz)));
    float n = tanhf(gn + r * (pn + bhn));
    float hnew = (1.f - z) * n + z * hprev;
    hprev = hnew;
    if (q == 0) {
      hbuf[(s + 1) & 1][j] = hnew;
      srow[(size_t)ts * 256 + j] = hnew;
    }
    __syncthreads();                   // hnew visible before next step's reads
    ts += stp;
    gx_c = gx_1; gx_1 = gx_2;
  }
  if (q == 0) (dir ? last_b : last_f)[b * 128 + j] = hprev;
}

// ---------------- doc_vec with torch .view batch-scramble ----------------
__global__ void docvec_kernel(const float* __restrict__ last_f, const float* __restrict__ last_b,
                              float* __restrict__ doc_vec) {
  int idx = blockIdx.x * 256 + threadIdx.x;  // 8192
  int i = idx >> 8, c = idx & 255;
  const float* src = (i < 16) ? last_f : last_b;
  int ii = (i < 16) ? i : i - 16;
  int bb = 2 * ii + (c >> 7);
  doc_vec[idx] = src[bb * 128 + (c & 127)];
}

// ---------------- topic_mat boundary diffs ----------------
__global__ void topicmat_kernel(const float* __restrict__ sent_rep, const int* __restrict__ tse,
                                float* __restrict__ topic_mat) {
  int bt = blockIdx.x;  // 512 = b*16+t
  int b = bt >> 4, t = bt & 15;
  int st = tse[(b * 16 + t) * 2 + 0];   // 1-based
  int en = tse[(b * 16 + t) * 2 + 1];
  int jj = threadIdx.x;                 // 0..255
  const float* sr = sent_rep + (size_t)b * 512 * 256;
  float val;
  if (jj < 128) {
    float a = sr[(size_t)(en - 1) * 256 + jj];
    float c = (st - 2 >= 0) ? sr[(size_t)(st - 2) * 256 + jj] : 0.f;
    val = a - c;
  } else {
    float a = sr[(size_t)(st - 1) * 256 + jj];
    float c = (en <= 511) ? sr[(size_t)en * 256 + jj] : 0.f;
    val = a - c;
  }
  topic_mat[(size_t)bt * 256 + jj] = val;
}

// ---------------- seg (searchsorted right - 1) ----------------
__global__ void seg_kernel(const int* __restrict__ tse, int* __restrict__ seg) {
  int idx = blockIdx.x * 256 + threadIdx.x;  // 16384
  int b = idx >> 9, s = idx & 511;
  int pos = s + 1, cnt = 0;
  for (int t = 0; t < T_; t++) cnt += (tse[(b * T_ + t) * 2] <= pos);
  int sg = cnt - 1; sg = sg < 0 ? 0 : (sg > T_ - 1 ? T_ - 1 : sg);
  seg[idx] = sg;
}

// ---------------- scores + ratios + context (wave per row) ----------------
__global__ void scores_ctx_kernel(const float* __restrict__ sr_part,     // [M,512]
                                  const float* __restrict__ doc_part,    // [32,512]
                                  const float* __restrict__ topic_part,  // [32,16,512]
                                  const float* __restrict__ v_att,       // [512]
                                  const float* __restrict__ doc_vec,     // [32,256]
                                  const float* __restrict__ topic_mat,   // [32,16,256]
                                  const int* __restrict__ seg,           // [M]
                                  float* __restrict__ context) {         // [M,256]
  int wid = threadIdx.x >> 6, lane = threadIdx.x & 63;
  int row = blockIdx.x * 4 + wid;
  int b = row >> 9;
  int sg = seg[row];
  const float* srp = sr_part + (size_t)row * 512;
  const float* dp = doc_part + (size_t)b * 512;
  const float* tp = topic_part + (size_t)(b * 16 + sg) * 512;
  float accd = 0.f, acct = 0.f;
  #pragma unroll
  for (int i = 0; i < 8; i++) {
    int n = lane + i * 64;
    float sp = srp[n], va = v_att[n];
    accd += tanhf(dp[n] + sp) * va;
    acct += tanhf(tp[n] + sp) * va;
  }
  #pragma unroll
  for (int off = 32; off; off >>= 1) { accd += __shfl_xor(accd, off); acct += __shfl_xor(acct, off); }
  float ssum = accd + acct;
  float rd = accd / ssum, rt = acct / ssum;
  const float* dv = doc_vec + (size_t)b * 256;
  const float* tm = topic_mat + (size_t)(b * 16 + sg) * 256;
  float* ctx = context + (size_t)row * 256;
  #pragma unroll
  for (int i = 0; i < 4; i++) {
    int jj = lane + i * 64;
    ctx[jj] = rd * dv[jj] + rt * tm[jj];
  }
}

// ---------------- logits: out = h . W2 + b2 (wave per row) ----------------
__global__ void logits_kernel(const float* __restrict__ h, const float* __restrict__ W2,
                              const float* __restrict__ b2, float* __restrict__ out, int M) {
  int wid = threadIdx.x >> 6, lane = threadIdx.x & 63;
  int row = blockIdx.x * 4 + wid;
  if (row >= M) return;
  const float* hp = h + (size_t)row * 128;
  float s = hp[lane] * W2[lane] + hp[lane + 64] * W2[lane + 64];
  #pragma unroll
  for (int off = 32; off; off >>= 1) s += __shfl_xor(s, off);
  if (lane == 0) out[row] = s + b2[0];
}

extern "C" void kernel_launch(void* const* d_in, const int* in_sizes, int n_in,
                              void* d_out, int out_size, void* d_ws, size_t ws_size,
                              hipStream_t stream) {
  const int*   word_ids = (const int*)d_in[0];
  const int*   tse      = (const int*)d_in[1];
  const float* emb      = (const float*)d_in[2];
  const float* Wih_f    = (const float*)d_in[3];
  const float* Whh_f    = (const float*)d_in[4];
  const float* bih_f    = (const float*)d_in[5];
  const float* bhh_f    = (const float*)d_in[6];
  const float* Wih_b    = (const float*)d_in[7];
  const float* Whh_b    = (const float*)d_in[8];
  const float* bih_b    = (const float*)d_in[9];
  const float* bhh_b    = (const float*)d_in[10];
  const float* W_att    = (const float*)d_in[11];
  const float* v_att    = (const float*)d_in[12];
  const float* W1       = (const float*)d_in[13];
  const float* b1       = (const float*)d_in[14];
  const float* W2       = (const float*)d_in[15];
  const float* b2       = (const float*)d_in[16];
  float* ws  = (float*)d_ws;
  float* out = (float*)d_out;

  prep_kernel<<<900, 256, 0, stream>>>(Wih_f, Wih_b, bih_f, bih_b, W1,
                                       ws + OFF_WTIH, ws + OFF_BIASIH, ws + OFF_W1T);
  embed_mean_kernel<<<M_, 128, 0, stream>>>(word_ids, emb, ws + OFF_X);
  // gx = x @ [Wih_f|Wih_b]^T + bias  -> [M,768]
  gemm64<true, false, false><<<dim3(12, 256), 256, 0, stream>>>(
      ws + OFF_X, E_, ws + OFF_WTIH, 768, ws + OFF_GX, 768, ws + OFF_BIASIH, M_, 768, E_);
  gru_kernel<<<64, 512, 0, stream>>>(ws + OFF_GX, Whh_f, Whh_b, bhh_f, bhh_b,
                                     ws + OFF_SENT, ws + OFF_LASTF, ws + OFF_LASTB);
  docvec_kernel<<<32, 256, 0, stream>>>(ws + OFF_LASTF, ws + OFF_LASTB, ws + OFF_DOCVEC);
  topicmat_kernel<<<512, 256, 0, stream>>>(ws + OFF_SENT, tse, ws + OFF_TOPICMAT);
  seg_kernel<<<64, 256, 0, stream>>>(tse, (int*)(ws + OFF_SEG));
  // doc_part = doc_vec @ W_att[0:256,:]
  gemm64<false, false, false><<<dim3(8, 1), 256, 0, stream>>>(
      ws + OFF_DOCVEC, 256, W_att, 512, ws + OFF_DOCPART, 512, nullptr, 32, 512, 256);
  // topic_part = topic_mat @ W_att[0:256,:]
  gemm64<false, false, false><<<dim3(8, 8), 256, 0, stream>>>(
      ws + OFF_TOPICMAT, 256, W_att, 512, ws + OFF_TOPICPART, 512, nullptr, 512, 512, 256);
  // sr_part = sent_rep @ W_att[256:512,:]
  gemm64<false, false, false><<<dim3(8, 256), 256, 0, stream>>>(
      ws + OFF_SENT, 256, W_att + 256 * 512, 512, ws + OFF_SRPART, 512, nullptr, M_, 512, 256);
  scores_ctx_kernel<<<M_ / 4, 256, 0, stream>>>(
      ws + OFF_SRPART, ws + OFF_DOCPART, ws + OFF_TOPICPART, v_att,
      ws + OFF_DOCVEC, ws + OFF_TOPICMAT, (const int*)(ws + OFF_SEG), ws + OFF_CTX);
  // h = relu(sent_rep @ W1t[0:256] + b1 + context @ W1t[256:512])
  gemm64<true, false, false><<<dim3(2, 256), 256, 0, stream>>>(
      ws + OFF_SENT, 256, ws + OFF_W1T, 128, ws + OFF_H, 128, b1, M_, 128, 256);
  gemm64<false, true, true><<<dim3(2, 256), 256, 0, stream>>>(
      ws + OFF_CTX, 256, ws + OFF_W1T + 256 * 128, 128, ws + OFF_H, 128, nullptr, M_, 128, 256);
  logits_kernel<<<M_ / 4, 256, 0, stream>>>(ws + OFF_H, W2, b2, out, M_);
}